// Round 5
// baseline (204.436 us; speedup 1.0000x reference)
//
#include <hip/hip_runtime.h>
#include <math.h>

typedef unsigned int U32;
typedef unsigned long long U64;

constexpr int N_SP   = 64 * 96 * 96;   // 589824 spatial positions per batch
constexpr int NBATCH = 2;
constexpr int K_TOP  = 2048;
constexpr int NBINS  = 8192;           // top 13 bits of monotonic float
constexpr int CAP    = 8192;           // candidate capacity per batch
constexpr float ANCHOR_F = 12.0f;
constexpr float NMS_IOU_F = 0.25f;

// ---- workspace layout (bytes) ----
constexpr size_t OFF_HIST = 0;                         // u32[2][8192]   = 65536
constexpr size_t OFF_CNT  = OFF_HIST + 2 * NBINS * 4;  // u32[2]
constexpr size_t OFF_THR  = OFF_CNT + 256;             // u32[2]
constexpr size_t OFF_RANK = OFF_THR + 256;             // u32[2][8192]   = 65536
constexpr size_t OFF_CAND = OFF_RANK + 2 * CAP * 4;    // u64[2][8192]   = 131072
constexpr size_t OFF_BOX  = OFF_CAND + 2 * CAP * 8;    // f32[2][14][2048] = 229376
constexpr size_t OFF_MASK = OFF_BOX + 2 * 14 * K_TOP * 4; // u32[2][2048][64] row-major = 1048576
// total ~1.47 MB

__device__ __forceinline__ U32 mono_of(float f) {
  U32 u = __float_as_uint(f);
  return (u & 0x80000000u) ? ~u : (u | 0x80000000u);
}
__device__ __forceinline__ float un_mono(U32 m) {
  U32 u = (m & 0x80000000u) ? (m ^ 0x80000000u) : ~m;
  return __uint_as_float(u);
}

// ---------------------------------------------------------------- zero scratch
__global__ void __launch_bounds__(256) k_zero(U32* hist, U32* rank, U32* cnt) {
  int g = blockIdx.x * 256 + threadIdx.x;  // 16384 threads
  hist[g] = 0;
  rank[g] = 0;
  if (g < NBATCH) cnt[g] = 0;
}

// ---------------------------------------------------------------- histogram
__global__ void __launch_bounds__(256) k_hist(const float* __restrict__ scores,
                                              U32* __restrict__ hist) {
  int b = blockIdx.y;
  const float4* s4 = (const float4*)(scores + (size_t)b * N_SP)
                     + (size_t)blockIdx.x * 2048 + threadIdx.x;
  float4 v[8];
#pragma unroll
  for (int e = 0; e < 8; ++e) v[e] = s4[e * 256];
  __shared__ U32 lh[NBINS];
  for (int k = threadIdx.x; k < NBINS; k += 256) lh[k] = 0;
  __syncthreads();
#pragma unroll
  for (int e = 0; e < 8; ++e) {
    atomicAdd(&lh[mono_of(v[e].x) >> 19], 1u);
    atomicAdd(&lh[mono_of(v[e].y) >> 19], 1u);
    atomicAdd(&lh[mono_of(v[e].z) >> 19], 1u);
    atomicAdd(&lh[mono_of(v[e].w) >> 19], 1u);
  }
  __syncthreads();
  U32* gh = hist + (size_t)b * NBINS;
  for (int k = threadIdx.x; k < NBINS; k += 256) {
    U32 c = lh[k];
    if (c) atomicAdd(&gh[k], c);
  }
}

// ---------------------------------------------------------------- find threshold bin
__global__ void __launch_bounds__(256) k_thresh(const U32* __restrict__ hist,
                                                U32* __restrict__ thr) {
  int b = blockIdx.x;
  const U32* h = hist + (size_t)b * NBINS;
  __shared__ U32 part[256];
  int t = threadIdx.x;
  int base = NBINS - 32 * (t + 1);  // chunk t covers [base, base+32), chunks descend
  U32 s = 0;
  for (int k = 0; k < 32; ++k) s += h[base + k];
  part[t] = s;
  __syncthreads();
  if (t == 0) {
    U32 cum = 0, bin = 0;
    for (int c = 0; c < 256; ++c) {
      U32 p = part[c];
      if (cum + p >= (U32)K_TOP) {
        int hb = NBINS - 32 * c - 1;
        for (int k = 0; k < 32; ++k) {
          cum += h[hb - k];
          if (cum >= (U32)K_TOP) { bin = (U32)(hb - k); break; }
        }
        break;
      }
      cum += p;
    }
    thr[b] = bin;  // keep all elements with bin >= thr
  }
}

// ---------------------------------------------------------------- collect candidates
__global__ void __launch_bounds__(256) k_collect(const float* __restrict__ scores,
                                                 const U32* __restrict__ thr,
                                                 U32* __restrict__ cnt,
                                                 U64* __restrict__ cand) {
  int b = blockIdx.y;
  U32 tb = thr[b];
  const float4* s4 = (const float4*)(scores + (size_t)b * N_SP)
                     + (size_t)blockIdx.x * 1024 + threadIdx.x;
  float4 v[4];
#pragma unroll
  for (int e = 0; e < 4; ++e) v[e] = s4[e * 256];
  __shared__ U64 lbuf[4096];   // worst case: every value in block passes
  __shared__ U32 lcnt, lbase;
  if (threadIdx.x == 0) lcnt = 0;
  __syncthreads();
#pragma unroll
  for (int e = 0; e < 4; ++e) {
    U32 i0 = (blockIdx.x * 1024 + e * 256 + threadIdx.x) * 4;
    float vv[4] = {v[e].x, v[e].y, v[e].z, v[e].w};
#pragma unroll
    for (int c = 0; c < 4; ++c) {
      U32 m = mono_of(vv[c]);
      if ((m >> 19) >= tb) {
        U32 p = atomicAdd(&lcnt, 1u);
        // key: score (monotonic) desc, then index asc (~idx desc)
        lbuf[p] = ((U64)m << 32) | (U32)(~(i0 + c));
      }
    }
  }
  __syncthreads();
  if (threadIdx.x == 0 && lcnt) lbase = atomicAdd(&cnt[b], lcnt);
  __syncthreads();
  U32 n = lcnt;
  if (n == 0) return;
  U32 base = lbase;
  U64* cb = cand + (size_t)b * CAP;
  for (U32 k = threadIdx.x; k < n; k += 256) {
    U32 pos = base + k;
    if (pos < (U32)CAP) cb[pos] = lbuf[k];
  }
}

// ---------------------------------------------------------------- rank by counting
__global__ void __launch_bounds__(256) k_count(const U64* __restrict__ cand,
                                               const U32* __restrict__ cnt,
                                               U32* __restrict__ rank) {
  int b = blockIdx.y;
  U32 C = cnt[b]; if (C > (U32)CAP) C = CAP;
  U32 g = blockIdx.x * 256 + threadIdx.x;  // 65536 per batch
  U32 t = g & (CAP - 1);
  U32 sgm = g >> 13;                        // 8 segments per key
  if (t >= C) return;
  const U64* cb = cand + (size_t)b * CAP;
  U64 key = cb[t];
  U32 segLen = (C + 7) >> 3;
  U32 j0 = sgm * segLen;
  U32 j1 = j0 + segLen; if (j1 > C) j1 = C;
  U32 c = 0;
  for (U32 j = j0; j < j1; ++j) c += (cb[j] > key) ? 1u : 0u;
  if (c) atomicAdd(&rank[(size_t)b * CAP + t], c);
}

// ---- exact-match FP from here on: no contraction (numpy does unfused mul/add)
#pragma clang fp contract(off)

// ---------------------------------------------------------------- gather + deparametrize
__global__ void __launch_bounds__(256) k_gather(const float* __restrict__ bboxes,
                                                const U64* __restrict__ cand,
                                                const U32* __restrict__ cnt,
                                                const U32* __restrict__ rank,
                                                float* __restrict__ box) {
  int b = blockIdx.y;
  U32 C = cnt[b]; if (C > (U32)CAP) C = CAP;
  U32 t = blockIdx.x * 256 + threadIdx.x;
  if (t >= C) return;
  U32 r = rank[(size_t)b * CAP + t];
  if (r >= (U32)K_TOP) return;
  U64 key = cand[(size_t)b * CAP + t];
  U32 idx = ~(U32)(key & 0xFFFFFFFFull);
  float sc = un_mono((U32)(key >> 32));
  int d = idx / 9216;
  int rem = idx - d * 9216;
  int h = rem / 96;
  int w = rem - h * 96;
  const float* src = bboxes + (size_t)b * 6 * N_SP + idx;
  float r0 = src[0];
  float r1 = src[(size_t)N_SP];
  float r2 = src[(size_t)2 * N_SP];
  float r3 = src[(size_t)3 * N_SP];
  float r4 = src[(size_t)4 * N_SP];
  float r5 = src[(size_t)5 * N_SP];
  float cz = r0 * ANCHOR_F + ((float)d + 0.5f);
  float cy = r1 * ANCHOR_F + ((float)h + 0.5f);
  float cx = r2 * ANCHOR_F + ((float)w + 0.5f);
  // double-precision exp then round: matches correctly-rounded f32 exp (np.exp)
  float sz = (float)exp((double)r3) * ANCHOR_F;
  float sy = (float)exp((double)r4) * ANCHOR_F;
  float sx = (float)exp((double)r5) * ANCHOR_F;
  float* B0 = box + (size_t)b * 14 * K_TOP;
  B0[0 * K_TOP + r] = cz;  B0[1 * K_TOP + r] = cy;  B0[2 * K_TOP + r] = cx;
  B0[3 * K_TOP + r] = sz;  B0[4 * K_TOP + r] = sy;  B0[5 * K_TOP + r] = sx;
  B0[6 * K_TOP + r] = cz - sz * 0.5f;   // c - s/2 (s*0.5 == s/2 exactly)
  B0[7 * K_TOP + r] = cy - sy * 0.5f;
  B0[8 * K_TOP + r] = cx - sx * 0.5f;
  B0[9 * K_TOP + r] = cz + sz * 0.5f;
  B0[10 * K_TOP + r] = cy + sy * 0.5f;
  B0[11 * K_TOP + r] = cx + sx * 0.5f;
  B0[12 * K_TOP + r] = (sz * sy) * sx;  // vol, left-fold like np.prod
  B0[13 * K_TOP + r] = sc;
}

// ---------------------------------------------------------------- IoU -> suppression bitmask
// ROW-major layout: mask[b][row i][word w] = bits for j in [32w, 32w+32)
__global__ void __launch_bounds__(256) k_mask(const float* __restrict__ box,
                                              U32* __restrict__ mask) {
  int b = blockIdx.y;
  int it = blockIdx.x >> 2;   // i-tile of 64 rows
  int jq = blockIdx.x & 3;    // j quarter of 512 cols
  const float* B0 = box + (size_t)b * 14 * K_TOP;
  __shared__ float ls[7][512];  // min0..2, max0..2, vol for the j-quarter
  int j0 = jq * 512;
  for (int k = threadIdx.x; k < 7 * 512; k += 256) {
    int a = k >> 9, j = k & 511;
    ls[a][j] = B0[(size_t)(6 + a) * K_TOP + j0 + j];
  }
  __syncthreads();
  int lane = threadIdx.x & 63;
  int wv = threadIdx.x >> 6;     // wave 0..3 -> 128-col slice
  int i = it * 64 + lane;
  float imin0 = B0[6 * K_TOP + i], imin1 = B0[7 * K_TOP + i], imin2 = B0[8 * K_TOP + i];
  float imax0 = B0[9 * K_TOP + i], imax1 = B0[10 * K_TOP + i], imax2 = B0[11 * K_TOP + i];
  float ivol  = B0[12 * K_TOP + i];
  U32 wbits[4];
  int jb = wv * 128;
#pragma unroll
  for (int wl = 0; wl < 4; ++wl) {
    U32 bits = 0;
    for (int bit = 0; bit < 32; ++bit) {
      int jl = jb + wl * 32 + bit;
      int j = j0 + jl;
      float lo0 = fmaxf(imin0, ls[0][jl]);
      float lo1 = fmaxf(imin1, ls[1][jl]);
      float lo2 = fmaxf(imin2, ls[2][jl]);
      float hi0 = fminf(imax0, ls[3][jl]);
      float hi1 = fminf(imax1, ls[4][jl]);
      float hi2 = fminf(imax2, ls[5][jl]);
      float d0 = fmaxf(hi0 - lo0, 0.0f);
      float d1 = fmaxf(hi1 - lo1, 0.0f);
      float d2 = fmaxf(hi2 - lo2, 0.0f);
      float inter = (d0 * d1) * d2;
      float uni = (ivol + ls[6][jl]) - inter;
      float iou = inter / uni;  // IEEE div, matches reference semantics
      bits |= ((iou > NMS_IOU_F) && (j > i)) ? (1u << bit) : 0u;
    }
    wbits[wl] = bits;
  }
  uint4* mrow = (uint4*)(mask + ((size_t)(b * K_TOP + i)) * 64);
  mrow[jq * 4 + wv] = make_uint4(wbits[0], wbits[1], wbits[2], wbits[3]);
}

// ---------------------------------------------------------------- blocked greedy NMS + output
// 2-phase producer-consumer: waves 1-3 issue global_load_lds (direct HBM->LDS,
// no dest registers => all 32 staging instrs outstanding at once) for chunk
// c+1 while wave 0 computes chunk c from LDS; the single __syncthreads() at
// loop end is the only drain (vmcnt(0) at barrier). Per-chunk wall =
// max(compute(c), stage-latency(c+1)) instead of sum — structural overlap the
// register pipeline failed to get (r4: 2000 cyc/block = full latency/block).
// LDS chunk is a verbatim contiguous copy of a contiguous global region, so
// the linear-dest constraint of global_load_lds holds. Consumer ds_read:
// lane l reads word l of each row -> bank l&31, 2-way alias (free, m136).
// Resolve math identical to round 4 (verified absmax=0): per 32-row block g,
// readlane'd diagonal words -> serial SALU alive-resolve; no writelane needed
// since dg[q] only has bits >q (j>i), so lane g of keep &= ~acc equals kw.
__global__ void __launch_bounds__(256) k_nms(const float* __restrict__ box,
                                             const U32* __restrict__ mask,
                                             float* __restrict__ out) {
  int b = blockIdx.x;
  int tid = threadIdx.x;
  int wv = tid >> 6, lane = tid & 63;
  const U32* mk = mask + (size_t)b * K_TOP * 64;
  __shared__ U32 sbuf[2][128 * 64];  // double-buffered 128-row chunks (2 x 32 KB)
  __shared__ U32 keepArr[64];

  // chunk cc = rows [cc*128, cc*128+128) = 8192 dwords; 32 instrs x 256 dwords.
  // Each instr: 64 lanes x 16 B = 1 KB, LDS dest uniform, global addr per-lane.
#define STAGE(cc, FIRST, STEP)                                                 \
  do {                                                                         \
    U32* dst = sbuf[(cc) & 1];                                                 \
    const U32* gsrc = mk + (size_t)(cc) * 8192;                                \
    for (int ins = (FIRST); ins < 32; ins += (STEP)) {                         \
      __builtin_amdgcn_global_load_lds(                                        \
          (const __attribute__((address_space(1))) U32*)(gsrc + ins * 256 +    \
                                                         lane * 4),            \
          (__attribute__((address_space(3))) U32*)(dst + ins * 256), 16, 0, 0);\
    }                                                                          \
  } while (0)

  STAGE(0, wv, 4);  // prologue: all 4 waves stage chunk 0
  __syncthreads();

  U32 keep = 0xFFFFFFFFu;  // lane l of wave 0 holds keep word l
  for (int c = 0; c < 16; ++c) {
    if (wv != 0) {
      if (c + 1 < 16) STAGE(c + 1, wv - 1, 3);
    } else {
      const U32* base = sbuf[c & 1];
      for (int blk = 0; blk < 4; ++blk) {
        int g = c * 4 + blk;  // global 32-row block index == diagonal word idx
        U32 rw[32];
#pragma unroll
        for (int q = 0; q < 32; ++q) rw[q] = base[(blk * 32 + q) * 64 + lane];
        U32 kw = (U32)__builtin_amdgcn_readlane((int)keep, g);
        U32 dg[32];
#pragma unroll
        for (int q = 0; q < 32; ++q)
          dg[q] = (U32)__builtin_amdgcn_readlane((int)rw[q], g);
        // serial intra-block resolve (uniform -> SALU chain); alive set
#pragma unroll
        for (int q = 0; q < 32; ++q)
          kw = (kw & (1u << q)) ? (kw & ~dg[q]) : kw;
        // parallel OR of alive rows' mask words
        U32 acc = 0;
#pragma unroll
        for (int q = 0; q < 32; ++q) {
          U32 sel = (kw & (1u << q)) ? 0xFFFFFFFFu : 0u;  // uniform s_cselect
          acc |= sel & rw[q];
        }
        keep &= ~acc;  // lane g gets exactly kw (see comment above)
      }
    }
    __syncthreads();  // drains staging vmcnt + publishes chunk c+1
  }
#undef STAGE

  if (wv == 0) keepArr[lane] = keep;
  __syncthreads();

  const float* B0 = box + (size_t)b * 14 * K_TOP;
  for (int t = tid; t < K_TOP; t += 256) {
    U32 kp = (keepArr[t >> 5] >> (t & 31)) & 1u;
    float sc = B0[13 * K_TOP + t];
    float vz = B0[0 * K_TOP + t], vy = B0[1 * K_TOP + t], vx = B0[2 * K_TOP + t];
    float dz = B0[3 * K_TOP + t], dy = B0[4 * K_TOP + t], dx = B0[5 * K_TOP + t];
    float* o = out + (size_t)(b * K_TOP + t) * 7;
    o[0] = kp ? sc : 0.0f;
    o[1] = kp ? vz : 0.0f;
    o[2] = kp ? vy : 0.0f;
    o[3] = kp ? vx : 0.0f;
    o[4] = kp ? dz : 0.0f;
    o[5] = kp ? dy : 0.0f;
    o[6] = kp ? dx : 0.0f;
  }
}

extern "C" void kernel_launch(void* const* d_in, const int* in_sizes, int n_in,
                              void* d_out, int out_size, void* d_ws, size_t ws_size,
                              hipStream_t stream) {
  const float* bboxes = (const float*)d_in[0];  // (2,6,64,96,96) f32
  const float* scores = (const float*)d_in[1];  // (2,64,96,96) f32
  float* out = (float*)d_out;                   // (2,2048,7) f32

  char* ws = (char*)d_ws;
  U32* hist = (U32*)(ws + OFF_HIST);
  U32* cnt  = (U32*)(ws + OFF_CNT);
  U32* thr  = (U32*)(ws + OFF_THR);
  U32* rank = (U32*)(ws + OFF_RANK);
  U64* cand = (U64*)(ws + OFF_CAND);
  float* box = (float*)(ws + OFF_BOX);
  U32* mask = (U32*)(ws + OFF_MASK);

  k_zero<<<64, 256, 0, stream>>>(hist, rank, cnt);
  k_hist<<<dim3(72, NBATCH), 256, 0, stream>>>(scores, hist);
  k_thresh<<<NBATCH, 256, 0, stream>>>(hist, thr);
  k_collect<<<dim3(144, NBATCH), 256, 0, stream>>>(scores, thr, cnt, cand);
  k_count<<<dim3(256, NBATCH), 256, 0, stream>>>(cand, cnt, rank);
  k_gather<<<dim3(CAP / 256, NBATCH), 256, 0, stream>>>(bboxes, cand, cnt, rank, box);
  k_mask<<<dim3(128, NBATCH), 256, 0, stream>>>(box, mask);
  k_nms<<<NBATCH, 256, 0, stream>>>(box, mask, out);
}

// Round 6
// 198.305 us; speedup vs baseline: 1.0309x; 1.0309x over previous
//
#include <hip/hip_runtime.h>
#include <math.h>

typedef unsigned int U32;
typedef unsigned long long U64;

constexpr int N_SP   = 64 * 96 * 96;   // 589824 spatial positions per batch
constexpr int NBATCH = 2;
constexpr int K_TOP  = 2048;
constexpr int NBINS  = 8192;           // top 13 bits of monotonic float
constexpr int CAP    = 8192;           // candidate capacity per batch
constexpr float ANCHOR_F = 12.0f;
constexpr float NMS_IOU_F = 0.25f;

// ---- workspace layout (bytes) ----
constexpr size_t OFF_HIST = 0;                         // u32[2][8192]   = 65536
constexpr size_t OFF_CNT  = OFF_HIST + 2 * NBINS * 4;  // u32[2]
constexpr size_t OFF_THR  = OFF_CNT + 256;             // u32[2]
constexpr size_t OFF_RANK = OFF_THR + 256;             // u32[2][8192]   = 65536
constexpr size_t OFF_CAND = OFF_RANK + 2 * CAP * 4;    // u64[2][8192]   = 131072
constexpr size_t OFF_BOX  = OFF_CAND + 2 * CAP * 8;    // f32[2][14][2048] = 229376
constexpr size_t OFF_MASK = OFF_BOX + 2 * 14 * K_TOP * 4; // u32[2][2048][64] row-major = 1048576
// total ~1.47 MB

__device__ __forceinline__ U32 mono_of(float f) {
  U32 u = __float_as_uint(f);
  return (u & 0x80000000u) ? ~u : (u | 0x80000000u);
}
__device__ __forceinline__ float un_mono(U32 m) {
  U32 u = (m & 0x80000000u) ? (m ^ 0x80000000u) : ~m;
  return __uint_as_float(u);
}

// ---------------------------------------------------------------- zero scratch
__global__ void __launch_bounds__(256) k_zero(U32* hist, U32* rank, U32* cnt) {
  int g = blockIdx.x * 256 + threadIdx.x;  // 16384 threads
  hist[g] = 0;
  rank[g] = 0;
  if (g < NBATCH) cnt[g] = 0;
}

// ---------------------------------------------------------------- histogram
__global__ void __launch_bounds__(256) k_hist(const float* __restrict__ scores,
                                              U32* __restrict__ hist) {
  int b = blockIdx.y;
  const float4* s4 = (const float4*)(scores + (size_t)b * N_SP)
                     + (size_t)blockIdx.x * 2048 + threadIdx.x;
  float4 v[8];
#pragma unroll
  for (int e = 0; e < 8; ++e) v[e] = s4[e * 256];
  __shared__ U32 lh[NBINS];
  for (int k = threadIdx.x; k < NBINS; k += 256) lh[k] = 0;
  __syncthreads();
#pragma unroll
  for (int e = 0; e < 8; ++e) {
    atomicAdd(&lh[mono_of(v[e].x) >> 19], 1u);
    atomicAdd(&lh[mono_of(v[e].y) >> 19], 1u);
    atomicAdd(&lh[mono_of(v[e].z) >> 19], 1u);
    atomicAdd(&lh[mono_of(v[e].w) >> 19], 1u);
  }
  __syncthreads();
  U32* gh = hist + (size_t)b * NBINS;
  for (int k = threadIdx.x; k < NBINS; k += 256) {
    U32 c = lh[k];
    if (c) atomicAdd(&gh[k], c);
  }
}

// ---------------------------------------------------------------- find threshold bin
__global__ void __launch_bounds__(256) k_thresh(const U32* __restrict__ hist,
                                                U32* __restrict__ thr) {
  int b = blockIdx.x;
  const U32* h = hist + (size_t)b * NBINS;
  __shared__ U32 part[256];
  int t = threadIdx.x;
  int base = NBINS - 32 * (t + 1);  // chunk t covers [base, base+32), chunks descend
  U32 s = 0;
  for (int k = 0; k < 32; ++k) s += h[base + k];
  part[t] = s;
  __syncthreads();
  if (t == 0) {
    U32 cum = 0, bin = 0;
    for (int c = 0; c < 256; ++c) {
      U32 p = part[c];
      if (cum + p >= (U32)K_TOP) {
        int hb = NBINS - 32 * c - 1;
        for (int k = 0; k < 32; ++k) {
          cum += h[hb - k];
          if (cum >= (U32)K_TOP) { bin = (U32)(hb - k); break; }
        }
        break;
      }
      cum += p;
    }
    thr[b] = bin;  // keep all elements with bin >= thr
  }
}

// ---------------------------------------------------------------- collect candidates
__global__ void __launch_bounds__(256) k_collect(const float* __restrict__ scores,
                                                 const U32* __restrict__ thr,
                                                 U32* __restrict__ cnt,
                                                 U64* __restrict__ cand) {
  int b = blockIdx.y;
  U32 tb = thr[b];
  const float4* s4 = (const float4*)(scores + (size_t)b * N_SP)
                     + (size_t)blockIdx.x * 1024 + threadIdx.x;
  float4 v[4];
#pragma unroll
  for (int e = 0; e < 4; ++e) v[e] = s4[e * 256];
  __shared__ U64 lbuf[4096];   // worst case: every value in block passes
  __shared__ U32 lcnt, lbase;
  if (threadIdx.x == 0) lcnt = 0;
  __syncthreads();
#pragma unroll
  for (int e = 0; e < 4; ++e) {
    U32 i0 = (blockIdx.x * 1024 + e * 256 + threadIdx.x) * 4;
    float vv[4] = {v[e].x, v[e].y, v[e].z, v[e].w};
#pragma unroll
    for (int c = 0; c < 4; ++c) {
      U32 m = mono_of(vv[c]);
      if ((m >> 19) >= tb) {
        U32 p = atomicAdd(&lcnt, 1u);
        // key: score (monotonic) desc, then index asc (~idx desc)
        lbuf[p] = ((U64)m << 32) | (U32)(~(i0 + c));
      }
    }
  }
  __syncthreads();
  if (threadIdx.x == 0 && lcnt) lbase = atomicAdd(&cnt[b], lcnt);
  __syncthreads();
  U32 n = lcnt;
  if (n == 0) return;
  U32 base = lbase;
  U64* cb = cand + (size_t)b * CAP;
  for (U32 k = threadIdx.x; k < n; k += 256) {
    U32 pos = base + k;
    if (pos < (U32)CAP) cb[pos] = lbuf[k];
  }
}

// ---------------------------------------------------------------- rank by counting
__global__ void __launch_bounds__(256) k_count(const U64* __restrict__ cand,
                                               const U32* __restrict__ cnt,
                                               U32* __restrict__ rank) {
  int b = blockIdx.y;
  U32 C = cnt[b]; if (C > (U32)CAP) C = CAP;
  U32 g = blockIdx.x * 256 + threadIdx.x;  // 65536 per batch
  U32 t = g & (CAP - 1);
  U32 sgm = g >> 13;                        // 8 segments per key
  if (t >= C) return;
  const U64* cb = cand + (size_t)b * CAP;
  U64 key = cb[t];
  U32 segLen = (C + 7) >> 3;
  U32 j0 = sgm * segLen;
  U32 j1 = j0 + segLen; if (j1 > C) j1 = C;
  U32 c = 0;
  for (U32 j = j0; j < j1; ++j) c += (cb[j] > key) ? 1u : 0u;
  if (c) atomicAdd(&rank[(size_t)b * CAP + t], c);
}

// ---- exact-match FP from here on: no contraction (numpy does unfused mul/add)
#pragma clang fp contract(off)

// ---------------------------------------------------------------- gather + deparametrize
__global__ void __launch_bounds__(256) k_gather(const float* __restrict__ bboxes,
                                                const U64* __restrict__ cand,
                                                const U32* __restrict__ cnt,
                                                const U32* __restrict__ rank,
                                                float* __restrict__ box) {
  int b = blockIdx.y;
  U32 C = cnt[b]; if (C > (U32)CAP) C = CAP;
  U32 t = blockIdx.x * 256 + threadIdx.x;
  if (t >= C) return;
  U32 r = rank[(size_t)b * CAP + t];
  if (r >= (U32)K_TOP) return;
  U64 key = cand[(size_t)b * CAP + t];
  U32 idx = ~(U32)(key & 0xFFFFFFFFull);
  float sc = un_mono((U32)(key >> 32));
  int d = idx / 9216;
  int rem = idx - d * 9216;
  int h = rem / 96;
  int w = rem - h * 96;
  const float* src = bboxes + (size_t)b * 6 * N_SP + idx;
  float r0 = src[0];
  float r1 = src[(size_t)N_SP];
  float r2 = src[(size_t)2 * N_SP];
  float r3 = src[(size_t)3 * N_SP];
  float r4 = src[(size_t)4 * N_SP];
  float r5 = src[(size_t)5 * N_SP];
  float cz = r0 * ANCHOR_F + ((float)d + 0.5f);
  float cy = r1 * ANCHOR_F + ((float)h + 0.5f);
  float cx = r2 * ANCHOR_F + ((float)w + 0.5f);
  // double-precision exp then round: matches correctly-rounded f32 exp (np.exp)
  float sz = (float)exp((double)r3) * ANCHOR_F;
  float sy = (float)exp((double)r4) * ANCHOR_F;
  float sx = (float)exp((double)r5) * ANCHOR_F;
  float* B0 = box + (size_t)b * 14 * K_TOP;
  B0[0 * K_TOP + r] = cz;  B0[1 * K_TOP + r] = cy;  B0[2 * K_TOP + r] = cx;
  B0[3 * K_TOP + r] = sz;  B0[4 * K_TOP + r] = sy;  B0[5 * K_TOP + r] = sx;
  B0[6 * K_TOP + r] = cz - sz * 0.5f;   // c - s/2 (s*0.5 == s/2 exactly)
  B0[7 * K_TOP + r] = cy - sy * 0.5f;
  B0[8 * K_TOP + r] = cx - sx * 0.5f;
  B0[9 * K_TOP + r] = cz + sz * 0.5f;
  B0[10 * K_TOP + r] = cy + sy * 0.5f;
  B0[11 * K_TOP + r] = cx + sx * 0.5f;
  B0[12 * K_TOP + r] = (sz * sy) * sx;  // vol, left-fold like np.prod
  B0[13 * K_TOP + r] = sc;
}

// ---------------------------------------------------------------- IoU -> suppression bitmask
// ROW-major layout: mask[b][row i][word w] = bits for j in [32w, 32w+32)
__global__ void __launch_bounds__(256) k_mask(const float* __restrict__ box,
                                              U32* __restrict__ mask) {
  int b = blockIdx.y;
  int it = blockIdx.x >> 2;   // i-tile of 64 rows
  int jq = blockIdx.x & 3;    // j quarter of 512 cols
  const float* B0 = box + (size_t)b * 14 * K_TOP;
  __shared__ float ls[7][512];  // min0..2, max0..2, vol for the j-quarter
  int j0 = jq * 512;
  for (int k = threadIdx.x; k < 7 * 512; k += 256) {
    int a = k >> 9, j = k & 511;
    ls[a][j] = B0[(size_t)(6 + a) * K_TOP + j0 + j];
  }
  __syncthreads();
  int lane = threadIdx.x & 63;
  int wv = threadIdx.x >> 6;     // wave 0..3 -> 128-col slice
  int i = it * 64 + lane;
  float imin0 = B0[6 * K_TOP + i], imin1 = B0[7 * K_TOP + i], imin2 = B0[8 * K_TOP + i];
  float imax0 = B0[9 * K_TOP + i], imax1 = B0[10 * K_TOP + i], imax2 = B0[11 * K_TOP + i];
  float ivol  = B0[12 * K_TOP + i];
  U32 wbits[4];
  int jb = wv * 128;
#pragma unroll
  for (int wl = 0; wl < 4; ++wl) {
    U32 bits = 0;
    for (int bit = 0; bit < 32; ++bit) {
      int jl = jb + wl * 32 + bit;
      int j = j0 + jl;
      float lo0 = fmaxf(imin0, ls[0][jl]);
      float lo1 = fmaxf(imin1, ls[1][jl]);
      float lo2 = fmaxf(imin2, ls[2][jl]);
      float hi0 = fminf(imax0, ls[3][jl]);
      float hi1 = fminf(imax1, ls[4][jl]);
      float hi2 = fminf(imax2, ls[5][jl]);
      float d0 = fmaxf(hi0 - lo0, 0.0f);
      float d1 = fmaxf(hi1 - lo1, 0.0f);
      float d2 = fmaxf(hi2 - lo2, 0.0f);
      float inter = (d0 * d1) * d2;
      float uni = (ivol + ls[6][jl]) - inter;
      float iou = inter / uni;  // IEEE div, matches reference semantics
      bits |= ((iou > NMS_IOU_F) && (j > i)) ? (1u << bit) : 0u;
    }
    wbits[wl] = bits;
  }
  uint4* mrow = (uint4*)(mask + ((size_t)(b * K_TOP + i)) * 64);
  mrow[jq * 4 + wv] = make_uint4(wbits[0], wbits[1], wbits[2], wbits[3]);
}

// ---------------------------------------------------------------- blocked greedy NMS + output
// T3+T4 (counted vmcnt, raw s_barrier — NEVER vmcnt(0) in the main loop).
// Round-5 post-mortem: __syncthreads() lowers to s_waitcnt vmcnt(0)+s_barrier,
// so each phase paid one full (~3.5us) load latency -> 16 x 3.47us = 55us.
// Now: 32 chunks of 64 rows (16 KB), 8 LDS buffers (128 KB), waves 1-2 stage
// chunk c+6 (8 global_load_lds each, uniform) then wait vmcnt(40) — i.e. only
// chunk c+1's 8 loads (oldest) must be done; chunks c+2..c+6 stay in flight
// across the raw barrier. Loads get ~6 phases (~3us) to land -> latency paid
// ~once. Wave 0's resolve math is byte-identical to rounds 4/5 (absmax=0).
// asm memory clobber after each barrier pins compiler code motion (rule 18).
__global__ void __launch_bounds__(256) k_nms(const float* __restrict__ box,
                                             const U32* __restrict__ mask,
                                             float* __restrict__ out) {
  int b = blockIdx.x;
  int tid = threadIdx.x;
  int wv = tid >> 6, lane = tid & 63;
  const U32* mk = mask + (size_t)b * K_TOP * 64;
  __shared__ U32 sbuf[8][64 * 64];  // 8 x 16 KB chunk buffers = 128 KB
  __shared__ U32 keepArr[64];

  // chunk cc = rows [cc*64, cc*64+64) = 4096 dwords; 16 instrs x 256 dwords,
  // split 8/8 across waves 1 and 2 (uniform count -> exact vmcnt arithmetic).
  // Each instr: 64 lanes x 16 B = 1 KB; LDS dest linear (dst + lane*16B).
#define STAGE(cc)                                                              \
  do {                                                                         \
    U32* dst = sbuf[(cc) & 7];                                                 \
    const U32* gsrc = mk + (size_t)(cc) * 4096;                                \
    _Pragma("unroll") for (int k = 0; k < 8; ++k) {                            \
      int ins = (wv - 1) * 8 + k;                                              \
      __builtin_amdgcn_global_load_lds(                                        \
          (const __attribute__((address_space(1))) U32*)(gsrc + ins * 256 +    \
                                                         lane * 4),            \
          (__attribute__((address_space(3))) U32*)(dst + ins * 256), 16, 0, 0);\
    }                                                                          \
  } while (0)

  if (wv == 1 || wv == 2) {
    for (int cc = 0; cc < 6; ++cc) STAGE(cc);                 // 48 outstanding
    asm volatile("s_waitcnt vmcnt(40)" ::: "memory");         // chunk 0 done
  }
  __builtin_amdgcn_s_barrier();
  asm volatile("" ::: "memory");

  U32 keep = 0xFFFFFFFFu;  // lane l of wave 0 holds keep word l
  for (int c = 0; c < 32; ++c) {
    if (wv == 0) {
      const U32* base = sbuf[c & 7];
      for (int blk = 0; blk < 2; ++blk) {
        int g = c * 2 + blk;  // global 32-row block index == diagonal word idx
        U32 rw[32];
#pragma unroll
        for (int q = 0; q < 32; ++q) rw[q] = base[(blk * 32 + q) * 64 + lane];
        U32 kw = (U32)__builtin_amdgcn_readlane((int)keep, g);
        U32 dg[32];
#pragma unroll
        for (int q = 0; q < 32; ++q)
          dg[q] = (U32)__builtin_amdgcn_readlane((int)rw[q], g);
        // serial intra-block resolve (uniform -> SALU chain); alive set
#pragma unroll
        for (int q = 0; q < 32; ++q)
          kw = (kw & (1u << q)) ? (kw & ~dg[q]) : kw;
        // parallel OR of alive rows' mask words
        U32 acc = 0;
#pragma unroll
        for (int q = 0; q < 32; ++q) {
          U32 sel = (kw & (1u << q)) ? 0xFFFFFFFFu : 0u;  // uniform s_cselect
          acc |= sel & rw[q];
        }
        keep &= ~acc;  // lane g gets exactly kw (j>i => dg[q] bits >q only)
      }
    } else if (wv <= 2) {
      if (c + 6 < 32) {
        STAGE(c + 6);
        // oldest 8 (chunk c+1) must retire; chunks c+2..c+6 (40) stay in flight
        asm volatile("s_waitcnt vmcnt(40)" ::: "memory");
      } else if (c == 26) { asm volatile("s_waitcnt vmcnt(32)" ::: "memory");
      } else if (c == 27) { asm volatile("s_waitcnt vmcnt(24)" ::: "memory");
      } else if (c == 28) { asm volatile("s_waitcnt vmcnt(16)" ::: "memory");
      } else if (c == 29) { asm volatile("s_waitcnt vmcnt(8)"  ::: "memory");
      } else              { asm volatile("s_waitcnt vmcnt(0)"  ::: "memory");
      }
    }
    __builtin_amdgcn_s_barrier();  // raw: no implicit vmcnt drain
    asm volatile("" ::: "memory");
  }
#undef STAGE

  if (wv == 0) keepArr[lane] = keep;
  __syncthreads();

  const float* B0 = box + (size_t)b * 14 * K_TOP;
  for (int t = tid; t < K_TOP; t += 256) {
    U32 kp = (keepArr[t >> 5] >> (t & 31)) & 1u;
    float sc = B0[13 * K_TOP + t];
    float vz = B0[0 * K_TOP + t], vy = B0[1 * K_TOP + t], vx = B0[2 * K_TOP + t];
    float dz = B0[3 * K_TOP + t], dy = B0[4 * K_TOP + t], dx = B0[5 * K_TOP + t];
    float* o = out + (size_t)(b * K_TOP + t) * 7;
    o[0] = kp ? sc : 0.0f;
    o[1] = kp ? vz : 0.0f;
    o[2] = kp ? vy : 0.0f;
    o[3] = kp ? vx : 0.0f;
    o[4] = kp ? dz : 0.0f;
    o[5] = kp ? dy : 0.0f;
    o[6] = kp ? dx : 0.0f;
  }
}

extern "C" void kernel_launch(void* const* d_in, const int* in_sizes, int n_in,
                              void* d_out, int out_size, void* d_ws, size_t ws_size,
                              hipStream_t stream) {
  const float* bboxes = (const float*)d_in[0];  // (2,6,64,96,96) f32
  const float* scores = (const float*)d_in[1];  // (2,64,96,96) f32
  float* out = (float*)d_out;                   // (2,2048,7) f32

  char* ws = (char*)d_ws;
  U32* hist = (U32*)(ws + OFF_HIST);
  U32* cnt  = (U32*)(ws + OFF_CNT);
  U32* thr  = (U32*)(ws + OFF_THR);
  U32* rank = (U32*)(ws + OFF_RANK);
  U64* cand = (U64*)(ws + OFF_CAND);
  float* box = (float*)(ws + OFF_BOX);
  U32* mask = (U32*)(ws + OFF_MASK);

  k_zero<<<64, 256, 0, stream>>>(hist, rank, cnt);
  k_hist<<<dim3(72, NBATCH), 256, 0, stream>>>(scores, hist);
  k_thresh<<<NBATCH, 256, 0, stream>>>(hist, thr);
  k_collect<<<dim3(144, NBATCH), 256, 0, stream>>>(scores, thr, cnt, cand);
  k_count<<<dim3(256, NBATCH), 256, 0, stream>>>(cand, cnt, rank);
  k_gather<<<dim3(CAP / 256, NBATCH), 256, 0, stream>>>(bboxes, cand, cnt, rank, box);
  k_mask<<<dim3(128, NBATCH), 256, 0, stream>>>(box, mask);
  k_nms<<<NBATCH, 256, 0, stream>>>(box, mask, out);
}